// Round 6
// baseline (2213.582 us; speedup 1.0000x reference)
//
#include <hip/hip_runtime.h>
#include <hip/hip_bf16.h>
#include <cstddef>

#define T_SEQ 512
#define BATCH 256
#define RTOT (BATCH * T_SEQ) /* 131072 rows */

typedef __attribute__((ext_vector_type(8))) short bf16x8;
typedef __attribute__((ext_vector_type(4))) float f32x4;

__device__ __forceinline__ float fsigmoid(float x) {
    return 1.0f / (1.0f + __expf(-x));
}
__device__ __forceinline__ float ftanh(float x) {
    return 1.0f - 2.0f / (__expf(2.0f * x) + 1.0f);
}
__device__ __forceinline__ unsigned short f2bf(float f) {
    union { float f; unsigned u; } v; v.f = f;
    // round-to-nearest-even bf16
    const unsigned r = (v.u + 0x7fffu + ((v.u >> 16) & 1u)) >> 16;
    return (unsigned short)r;
}

// ---------------------------------------------------------------------------
// Input projection: xp[r, 0:192] = x[r, :] @ W + bi   for both directions.
// (unchanged from round 2 — not the bottleneck yet)
// ---------------------------------------------------------------------------
template <int DIN, bool EMBED>
__global__ __launch_bounds__(192) void proj_kernel(
    const float* __restrict__ X, const int* __restrict__ tokens,
    const float* __restrict__ emb,
    const float* __restrict__ Wf, const float* __restrict__ bf_,
    const float* __restrict__ Wb, const float* __restrict__ bb_,
    float* __restrict__ xpf, float* __restrict__ xpb)
{
    constexpr int ROWS = 32;
    constexpr int PAD = 36;
    __shared__ __align__(16) float xt[DIN][PAD];
    const int r0 = blockIdx.x * ROWS;
    const int tid = threadIdx.x;

    for (int e = tid; e < ROWS * DIN; e += 192) {
        const int row = e / DIN;
        const int i = e % DIN;
        float v;
        if (EMBED) {
            v = emb[(size_t)tokens[r0 + row] * 64 + i];
        } else {
            v = X[(size_t)(r0 + row) * DIN + i];
        }
        xt[i][row] = v;
    }
    __syncthreads();

    const int col = tid;
    #pragma unroll
    for (int d = 0; d < 2; d++) {
        const float* __restrict__ W = d ? Wb : Wf;
        const float* __restrict__ bi = d ? bb_ : bf_;
        float* __restrict__ outp = d ? xpb : xpf;
        float acc[ROWS];
        const float b0 = bi[col];
        #pragma unroll
        for (int r = 0; r < ROWS; r++) acc[r] = b0;
        #pragma unroll 4
        for (int i = 0; i < DIN; i++) {
            const float w = W[i * 192 + col];
            #pragma unroll
            for (int r = 0; r < ROWS; r += 4) {
                const float4 x4 = *(const float4*)&xt[i][r];
                acc[r + 0] = fmaf(x4.x, w, acc[r + 0]);
                acc[r + 1] = fmaf(x4.y, w, acc[r + 1]);
                acc[r + 2] = fmaf(x4.z, w, acc[r + 2]);
                acc[r + 3] = fmaf(x4.w, w, acc[r + 3]);
            }
        }
        #pragma unroll
        for (int r = 0; r < ROWS; r++) {
            outp[(size_t)(r0 + r) * 192 + col] = acc[r];
        }
    }
}

// ---------------------------------------------------------------------------
// MFMA batched recurrent scan.
// One 256-thread block (4 waves) = 16 chains of one direction.
// Per step: Rec[16,192] = H[16,64] @ Wh[64,192] via 24 mfma_f32_16x16x32_bf16
// (wave w owns output dim-slice [16w,16w+16): its z/r/c column tiles).
// Wh B-fragments live in 24 VGPRs per lane (loaded once) -> ZERO per-step
// weight traffic (rounds 3-5 showed weight streaming costs 800-1800 cyc/step).
// h master state is fp32 in registers (C-layout: lane -> 4 chains x 1 dim);
// only MFMA inputs are bf16 (double-buffered 2KB LDS, one barrier/step).
// Layouts (HW-verified per guide):
//   C/D: col=lane&15 (dim), row=(lane>>4)*4+reg (chain)
//   A:   m=lane&15 (chain), k=(lane>>4)*8+j (dim)
//   B:   n=lane&15 (out col), k=(lane>>4)*8+j (in dim)
// ---------------------------------------------------------------------------
__global__ __launch_bounds__(256) void gru_scan_mfma(
    const float* __restrict__ xpf, const float* __restrict__ xpb,
    const float* __restrict__ whf, const float* __restrict__ whb,
    const float* __restrict__ bbf, const float* __restrict__ bbb,
    const int* __restrict__ tokens,
    float* __restrict__ y,        // [RTOT,128] or nullptr
    float* __restrict__ hfinal)   // [BATCH,128] or nullptr
{
    const int dir = blockIdx.x & 1;
    const int b0 = (blockIdx.x >> 1) * 16;
    const float* __restrict__ xp = dir ? xpb : xpf;
    const float* __restrict__ wh = dir ? whb : whf;
    const float* __restrict__ bbv = dir ? bbb : bbf;

    const int tid = threadIdx.x;
    const int w = tid >> 6;      // wave 0..3 -> dim slice [16w,16w+16)
    const int lane = tid & 63;
    const int n = lane & 15;     // tile col (dim within slice) / A row (chain)
    const int quad = lane >> 4;  // k-octet / C row-group

    // --- B-fragments: persistent weights (24 VGPRs) ---
    bf16x8 Bz[2], Br[2], Bc[2];
    #pragma unroll
    for (int h = 0; h < 2; h++) {
        #pragma unroll
        for (int j = 0; j < 8; j++) {
            const int k = quad * 8 + j + 32 * h; // input dim
            const int cb = 16 * w + n;           // output dim within gate
            Bz[h][j] = (short)f2bf(wh[k * 192 + cb]);
            Br[h][j] = (short)f2bf(wh[k * 192 + 64 + cb]);
            Bc[h][j] = (short)f2bf(wh[k * 192 + 128 + cb]);
        }
    }
    const float bhz = bbv[192 + 16 * w + n];
    const float bhr = bbv[192 + 64 + 16 * w + n];
    const float bhc = bbv[192 + 128 + 16 * w + n];

    __shared__ __align__(16) unsigned short Hb[2][16][64]; // bf16 H, dbl-buf
    __shared__ float msk[16][T_SEQ];                       // 32 KB

    for (int i = tid; i < 16 * T_SEQ; i += 256) {
        const int c = i >> 9, t = i & (T_SEQ - 1);
        msk[c][t] = (tokens[(size_t)(b0 + c) * T_SEQ + t] > 0) ? 1.0f : 0.0f;
    }
    for (int i = tid; i < 16 * 64; i += 256) {
        ((unsigned short*)Hb[0])[i] = 0; // bf16 +0.0
    }

    const int t0 = dir ? (T_SEQ - 1) : 0;
    const int st = dir ? -1 : 1;

    // per-reg (chain) xp row offsets and y pointers
    float h[4] = {0.f, 0.f, 0.f, 0.f};
    size_t xrow[4];
    float* yptr[4];
    #pragma unroll
    for (int r = 0; r < 4; r++) {
        const int chain = quad * 4 + r;
        xrow[r] = ((size_t)(b0 + chain) * T_SEQ + t0) * 192;
        yptr[r] = y ? (y + ((size_t)(b0 + chain) * T_SEQ + t0) * 128
                         + (dir << 6) + 16 * w + n) : nullptr;
    }
    const ptrdiff_t ystep = (ptrdiff_t)st * 128;
    const int cz = 16 * w + n, cr = 64 + 16 * w + n, cc = 128 + 16 * w + n;

    // initial xp load (t0)
    float xz[4], xr[4], xc[4];
    #pragma unroll
    for (int r = 0; r < 4; r++) {
        xz[r] = xp[xrow[r] + cz];
        xr[r] = xp[xrow[r] + cr];
        xc[r] = xp[xrow[r] + cc];
    }

    __syncthreads();

    int p = 0;
    int te = t0;
    for (int t = 0; t < T_SEQ; t++) {
        // A-fragments of previous h (bf16) — 2 x ds_read_b128
        const bf16x8 A0 = *(const bf16x8*)&Hb[p][n][quad * 8];
        const bf16x8 A1 = *(const bf16x8*)&Hb[p][n][32 + quad * 8];

        f32x4 az = {bhz, bhz, bhz, bhz};
        f32x4 ar = {bhr, bhr, bhr, bhr};
        f32x4 ac = {bhc, bhc, bhc, bhc};
        az = __builtin_amdgcn_mfma_f32_16x16x32_bf16(A0, Bz[0], az, 0, 0, 0);
        ar = __builtin_amdgcn_mfma_f32_16x16x32_bf16(A0, Br[0], ar, 0, 0, 0);
        ac = __builtin_amdgcn_mfma_f32_16x16x32_bf16(A0, Bc[0], ac, 0, 0, 0);
        az = __builtin_amdgcn_mfma_f32_16x16x32_bf16(A1, Bz[1], az, 0, 0, 0);
        ar = __builtin_amdgcn_mfma_f32_16x16x32_bf16(A1, Br[1], ar, 0, 0, 0);
        ac = __builtin_amdgcn_mfma_f32_16x16x32_bf16(A1, Bc[1], ac, 0, 0, 0);

        // prefetch next step's xp while MFMA runs
        float pz[4], pr[4], pc[4];
        const ptrdiff_t adv = (t + 1 < T_SEQ) ? (ptrdiff_t)st * 192 : 0;
        #pragma unroll
        for (int r = 0; r < 4; r++) {
            const size_t nrow = xrow[r] + adv;
            pz[r] = xp[nrow + cz];
            pr[r] = xp[nrow + cr];
            pc[r] = xp[nrow + cc];
            xrow[r] = nrow;
        }

        // gates + state update (fp32), write new bf16 H
        #pragma unroll
        for (int r = 0; r < 4; r++) {
            const int chain = quad * 4 + r;
            const float m  = msk[chain][te];
            const float z  = fsigmoid(xz[r] + az[r]);
            const float rr = fsigmoid(xr[r] + ar[r]);
            const float hh = ftanh(xc[r] + rr * ac[r]);
            const float hn = z * h[r] + (1.0f - z) * hh;
            h[r] = fmaf(m, hn - h[r], h[r]); // exact carry when m==0
            if (y) { *yptr[r] = h[r]; yptr[r] += ystep; }
            Hb[p ^ 1][chain][16 * w + n] = f2bf(h[r]);
        }
        __syncthreads(); // new H visible; buffers swap
        p ^= 1;
        te += st;
        #pragma unroll
        for (int r = 0; r < 4; r++) {
            xz[r] = pz[r]; xr[r] = pr[r]; xc[r] = pc[r];
        }
    }

    if (hfinal) {
        #pragma unroll
        for (int r = 0; r < 4; r++) {
            const int chain = quad * 4 + r;
            hfinal[(size_t)(b0 + chain) * 128 + (dir << 6) + 16 * w + n] = h[r];
        }
    }
}

// ---------------------------------------------------------------------------
// MLP head: one block (1 wave) per batch row.
// ---------------------------------------------------------------------------
__global__ __launch_bounds__(64) void mlp_kernel(
    const float* __restrict__ hcat, // [BATCH,128]
    const float* __restrict__ wd1, const float* __restrict__ bd1,
    const float* __restrict__ wd2, const float* __restrict__ bd2,
    const float* __restrict__ wd3, const float* __restrict__ bd3,
    const float* __restrict__ wo, const float* __restrict__ bo,
    float* __restrict__ outp)       // [BATCH,28]
{
    const int b = blockIdx.x;
    const int j = threadIdx.x;
    __shared__ float x0[128];
    __shared__ float x1[64];
    x0[j] = hcat[b * 128 + j];
    x0[j + 64] = hcat[b * 128 + 64 + j];
    __syncthreads();
    float a = bd1[j];
    #pragma unroll 4
    for (int i = 0; i < 128; i++) a = fmaf(x0[i], wd1[i * 64 + j], a);
    a = fmaxf(a, 0.0f);
    x1[j] = a;
    __syncthreads();
    float a2 = bd2[j];
    #pragma unroll 4
    for (int i = 0; i < 64; i++) a2 = fmaf(x1[i], wd2[i * 64 + j], a2);
    a2 = fmaxf(a2, 0.0f);
    __syncthreads();
    x1[j] = a2;
    __syncthreads();
    float a3 = bd3[j];
    #pragma unroll 4
    for (int i = 0; i < 64; i++) a3 = fmaf(x1[i], wd3[i * 64 + j], a3);
    a3 = fmaxf(a3, 0.0f);
    __syncthreads();
    x1[j] = a3;
    __syncthreads();
    if (j < 28) {
        float o = bo[j];
        #pragma unroll 4
        for (int i = 0; i < 64; i++) o = fmaf(x1[i], wo[i * 28 + j], o);
        outp[b * 28 + j] = fsigmoid(o);
    }
}

// ---------------------------------------------------------------------------
extern "C" void kernel_launch(void* const* d_in, const int* in_sizes, int n_in,
                              void* d_out, int out_size, void* d_ws, size_t ws_size,
                              hipStream_t stream)
{
    const int* tokens  = (const int*)d_in[0];
    const float* emb   = (const float*)d_in[1];
    const float* wi1f  = (const float*)d_in[2];
    const float* wh1f  = (const float*)d_in[3];
    const float* bb1f  = (const float*)d_in[4];
    const float* wi1b  = (const float*)d_in[5];
    const float* wh1b  = (const float*)d_in[6];
    const float* bb1b  = (const float*)d_in[7];
    const float* wi2f  = (const float*)d_in[8];
    const float* wh2f  = (const float*)d_in[9];
    const float* bb2f  = (const float*)d_in[10];
    const float* wi2b  = (const float*)d_in[11];
    const float* wh2b  = (const float*)d_in[12];
    const float* bb2b  = (const float*)d_in[13];
    const float* wi3f  = (const float*)d_in[14];
    const float* wh3f  = (const float*)d_in[15];
    const float* bb3f  = (const float*)d_in[16];
    const float* wi3b  = (const float*)d_in[17];
    const float* wh3b  = (const float*)d_in[18];
    const float* bb3b  = (const float*)d_in[19];
    const float* wd1   = (const float*)d_in[20];
    const float* bd1   = (const float*)d_in[21];
    const float* wd2   = (const float*)d_in[22];
    const float* bd2   = (const float*)d_in[23];
    const float* wd3   = (const float*)d_in[24];
    const float* bd3   = (const float*)d_in[25];
    const float* wo    = (const float*)d_in[26];
    const float* bo    = (const float*)d_in[27];

    // Workspace (exactly 256 MiB):
    float* y    = (float*)d_ws;
    float* xpf  = y + (size_t)RTOT * 128;
    float* xpb  = xpf + (size_t)RTOT * 192;
    float* hcat = y; // alias: y dead after proj3 reads it

    const dim3 pb(192), pg(RTOT / 32);

    proj_kernel<64, true><<<pg, pb, 0, stream>>>(nullptr, tokens, emb,
                                                 wi1f, bb1f, wi1b, bb1b, xpf, xpb);
    gru_scan_mfma<<<32, 256, 0, stream>>>(xpf, xpb, wh1f, wh1b, bb1f, bb1b,
                                          tokens, y, nullptr);
    proj_kernel<128, false><<<pg, pb, 0, stream>>>(y, nullptr, nullptr,
                                                   wi2f, bb2f, wi2b, bb2b, xpf, xpb);
    gru_scan_mfma<<<32, 256, 0, stream>>>(xpf, xpb, wh2f, wh2b, bb2f, bb2b,
                                          tokens, y, nullptr);
    proj_kernel<128, false><<<pg, pb, 0, stream>>>(y, nullptr, nullptr,
                                                   wi3f, bb3f, wi3b, bb3b, xpf, xpb);
    gru_scan_mfma<<<32, 256, 0, stream>>>(xpf, xpb, wh3f, wh3b, bb3f, bb3b,
                                          tokens, nullptr, hcat);
    mlp_kernel<<<256, 64, 0, stream>>>(hcat, wd1, bd1, wd2, bd2, wd3, bd3,
                                       wo, bo, (float*)d_out);
}

// Round 7
// 2089.442 us; speedup vs baseline: 1.0594x; 1.0594x over previous
//
#include <hip/hip_runtime.h>
#include <hip/hip_bf16.h>
#include <cstddef>

#define T_SEQ 512
#define BATCH 256
#define RTOT (BATCH * T_SEQ) /* 131072 rows */

__device__ __forceinline__ float fsigmoid(float x) {
    return 1.0f / (1.0f + __expf(-x));
}
__device__ __forceinline__ float ftanh(float x) {
    return 1.0f - 2.0f / (__expf(2.0f * x) + 1.0f);
}

// ---------------------------------------------------------------------------
// Input projection (unchanged from round 2): xp[r,0:192] = x[r,:]@W + bi.
// ---------------------------------------------------------------------------
template <int DIN, bool EMBED>
__global__ __launch_bounds__(192) void proj_kernel(
    const float* __restrict__ X, const int* __restrict__ tokens,
    const float* __restrict__ emb,
    const float* __restrict__ Wf, const float* __restrict__ bf_,
    const float* __restrict__ Wb, const float* __restrict__ bb_,
    float* __restrict__ xpf, float* __restrict__ xpb)
{
    constexpr int ROWS = 32;
    constexpr int PAD = 36;
    __shared__ __align__(16) float xt[DIN][PAD];
    const int r0 = blockIdx.x * ROWS;
    const int tid = threadIdx.x;

    for (int e = tid; e < ROWS * DIN; e += 192) {
        const int row = e / DIN;
        const int i = e % DIN;
        float v;
        if (EMBED) {
            v = emb[(size_t)tokens[r0 + row] * 64 + i];
        } else {
            v = X[(size_t)(r0 + row) * DIN + i];
        }
        xt[i][row] = v;
    }
    __syncthreads();

    const int col = tid;
    #pragma unroll
    for (int d = 0; d < 2; d++) {
        const float* __restrict__ W = d ? Wb : Wf;
        const float* __restrict__ bi = d ? bb_ : bf_;
        float* __restrict__ outp = d ? xpb : xpf;
        float acc[ROWS];
        const float b0 = bi[col];
        #pragma unroll
        for (int r = 0; r < ROWS; r++) acc[r] = b0;
        #pragma unroll 4
        for (int i = 0; i < DIN; i++) {
            const float w = W[i * 192 + col];
            #pragma unroll
            for (int r = 0; r < ROWS; r += 4) {
                const float4 x4 = *(const float4*)&xt[i][r];
                acc[r + 0] = fmaf(x4.x, w, acc[r + 0]);
                acc[r + 1] = fmaf(x4.y, w, acc[r + 1]);
                acc[r + 2] = fmaf(x4.z, w, acc[r + 2]);
                acc[r + 3] = fmaf(x4.w, w, acc[r + 3]);
            }
        }
        #pragma unroll
        for (int r = 0; r < ROWS; r++) {
            outp[(size_t)(r0 + r) * 192 + col] = acc[r];
        }
    }
}

// ---------------------------------------------------------------------------
// Recurrent scan v4: 192 threads (3 waves = z/r/c gate), TWO chains per block
// (same direction -> shared weights), Wh resident in LDS.
//
// Why: rounds 3/4 proved VGPR weight residency is unobtainable; round 2/5/6
// showed L2-stream (1550 cyc/step), conflicted-LDS (24 cyc/read) and MFMA
// (32-block occupancy collapse) all lose. Here: Wh staged ONCE in LDS
// chunk-major wlds4[i*192+col] so lane reads are the conflict-free
// contiguous-16B b128 pattern with immediate offsets; each read feeds 2
// chains' FMAs; grid=256 covers every CU.
//
// Per step, lane tid (gate w=tid/64, col j=tid%63): a[c] = h[c] . Wh[:,tid],
// 16 b128 weight reads + 32 broadcast h reads + 128 FMA. Wave0->z, wave1->r,
// wave2: a is the c-gate rec; after B1 it combines z,r (LDS) with its own
// master h (registers), updates, writes h pairs + y. B2 publishes h.
// ---------------------------------------------------------------------------
__global__ __launch_bounds__(192) void gru_scan2(
    const float* __restrict__ xpf, const float* __restrict__ xpb,
    const float* __restrict__ whf, const float* __restrict__ whb,
    const float* __restrict__ bbf, const float* __restrict__ bbb,
    const int* __restrict__ tokens,
    float* __restrict__ y,        // [RTOT,128] or nullptr
    float* __restrict__ hfinal)   // [BATCH,128] or nullptr
{
    const int dir = blockIdx.x & 1;
    const int b0 = (blockIdx.x >> 1) * 2;   // two batches per block
    const float* __restrict__ xp = dir ? xpb : xpf;
    const float* __restrict__ wh = dir ? whb : whf;
    const float* __restrict__ bbv = dir ? bbb : bbf;
    const int tid = threadIdx.x;  // 0..191 = gate column
    const int w = tid >> 6;       // 0=z, 1=r, 2=c
    const int j = tid & 63;

    __shared__ __align__(16) float4 wlds4[16 * 192]; // 48 KiB [chunk][col]
    __shared__ __align__(16) float2 hp[64];          // h[dim] = {c0, c1}
    __shared__ __align__(16) float2 zp[64];
    __shared__ __align__(16) float2 rp[64];
    __shared__ __align__(16) float2 mp[T_SEQ];       // mask[t] = {c0, c1}

    // One-time staging: Wh column tid, chunks of 4 rows (coalesced in tid).
    #pragma unroll 4
    for (int i = 0; i < 16; i++) {
        float4 w4;
        w4.x = wh[(4 * i + 0) * 192 + tid];
        w4.y = wh[(4 * i + 1) * 192 + tid];
        w4.z = wh[(4 * i + 2) * 192 + tid];
        w4.w = wh[(4 * i + 3) * 192 + tid];
        wlds4[i * 192 + tid] = w4;
    }
    for (int i = tid; i < T_SEQ * 2; i += 192) {
        const int t = i >> 1, c = i & 1;
        ((float*)mp)[i] =
            (tokens[(size_t)(b0 + c) * T_SEQ + t] > 0) ? 1.0f : 0.0f;
    }
    if (w == 0) { hp[j].x = 0.0f; hp[j].y = 0.0f; }
    const float bh = bbv[192 + tid]; // recurrent bias (bb row 1)
    float h0 = 0.0f, h1 = 0.0f;      // master state (meaningful on wave2)

    const int t0 = dir ? (T_SEQ - 1) : 0;
    const int st = dir ? -1 : 1;
    const ptrdiff_t rstep = (ptrdiff_t)st * 192;
    const float* xr0 = xp + ((size_t)b0 * T_SEQ + t0) * 192;       // chain 0
    const float* xr1 = xp + ((size_t)(b0 + 1) * T_SEQ + t0) * 192; // chain 1
    // current + next xp values (distance-2 prefetch pipeline)
    float x00 = xr0[tid], x01 = xr1[tid];
    float x10 = xr0[rstep + tid], x11 = xr1[rstep + tid];

    float* y0 = y ? (y + ((size_t)b0 * T_SEQ + t0) * 128 + (dir << 6) + j)
                  : nullptr;
    float* y1 = y ? (y + ((size_t)(b0 + 1) * T_SEQ + t0) * 128 + (dir << 6) + j)
                  : nullptr;
    const ptrdiff_t ystep = (ptrdiff_t)st * 128;
    int te = t0;

    __syncthreads(); // staging visible

    for (int t = 0; t < T_SEQ; t++) {
        // prefetch t+2 (tail-guarded)
        const ptrdiff_t adv = (t + 2 < T_SEQ) ? 2 * rstep : 0;
        const float p0 = xr0[adv + tid];
        const float p1 = xr1[adv + tid];

        // a[c] = h[c] . Wh[:,tid] + bh   (weights from LDS, h broadcast)
        float a0 = bh, a1 = bh;
        #pragma unroll
        for (int i = 0; i < 16; i++) {
            const float4 w4 = wlds4[i * 192 + tid];        // b128, imm offset
            const float4 q0 = *(const float4*)&hp[4 * i];      // h[4i],h[4i+1]
            const float4 q1 = *(const float4*)&hp[4 * i + 2];  // h[4i+2],h[4i+3]
            a0 = fmaf(w4.x, q0.x, a0); a1 = fmaf(w4.x, q0.y, a1);
            a0 = fmaf(w4.y, q0.z, a0); a1 = fmaf(w4.y, q0.w, a1);
            a0 = fmaf(w4.z, q1.x, a0); a1 = fmaf(w4.z, q1.y, a1);
            a0 = fmaf(w4.w, q1.z, a0); a1 = fmaf(w4.w, q1.w, a1);
        }
        if (w == 0) {
            zp[j].x = fsigmoid(x00 + a0);
            zp[j].y = fsigmoid(x01 + a1);
        } else if (w == 1) {
            rp[j].x = fsigmoid(x00 + a0);
            rp[j].y = fsigmoid(x01 + a1);
        }
        __syncthreads(); // B1: gates visible to wave2
        if (w == 2) {
            const float2 r2 = rp[j];
            const float2 z2 = zp[j];
            const float2 m2 = mp[te]; // uniform -> broadcast
            const float hh0 = ftanh(x00 + r2.x * a0);
            const float hh1 = ftanh(x01 + r2.y * a1);
            const float hn0 = z2.x * h0 + (1.0f - z2.x) * hh0;
            const float hn1 = z2.y * h1 + (1.0f - z2.y) * hh1;
            h0 = fmaf(m2.x, hn0 - h0, h0); // exact carry when masked
            h1 = fmaf(m2.y, hn1 - h1, h1);
            hp[j].x = h0;
            hp[j].y = h1;
            if (y) {
                *y0 = h0; y0 += ystep;
                *y1 = h1; y1 += ystep;
            }
        }
        __syncthreads(); // B2: new h published
        x00 = x10; x01 = x11;
        x10 = p0;  x11 = p1;
        xr0 += rstep;
        xr1 += rstep;
        te += st;
    }
    if (hfinal && w == 2) {
        hfinal[(size_t)b0 * 128 + (dir << 6) + j] = h0;
        hfinal[(size_t)(b0 + 1) * 128 + (dir << 6) + j] = h1;
    }
}

// ---------------------------------------------------------------------------
// MLP head: one block (1 wave) per batch row.
// ---------------------------------------------------------------------------
__global__ __launch_bounds__(64) void mlp_kernel(
    const float* __restrict__ hcat, // [BATCH,128]
    const float* __restrict__ wd1, const float* __restrict__ bd1,
    const float* __restrict__ wd2, const float* __restrict__ bd2,
    const float* __restrict__ wd3, const float* __restrict__ bd3,
    const float* __restrict__ wo, const float* __restrict__ bo,
    float* __restrict__ outp)       // [BATCH,28]
{
    const int b = blockIdx.x;
    const int j = threadIdx.x;
    __shared__ float x0[128];
    __shared__ float x1[64];
    x0[j] = hcat[b * 128 + j];
    x0[j + 64] = hcat[b * 128 + 64 + j];
    __syncthreads();
    float a = bd1[j];
    #pragma unroll 4
    for (int i = 0; i < 128; i++) a = fmaf(x0[i], wd1[i * 64 + j], a);
    a = fmaxf(a, 0.0f);
    x1[j] = a;
    __syncthreads();
    float a2 = bd2[j];
    #pragma unroll 4
    for (int i = 0; i < 64; i++) a2 = fmaf(x1[i], wd2[i * 64 + j], a2);
    a2 = fmaxf(a2, 0.0f);
    __syncthreads();
    x1[j] = a2;
    __syncthreads();
    float a3 = bd3[j];
    #pragma unroll 4
    for (int i = 0; i < 64; i++) a3 = fmaf(x1[i], wd3[i * 64 + j], a3);
    a3 = fmaxf(a3, 0.0f);
    __syncthreads();
    x1[j] = a3;
    __syncthreads();
    if (j < 28) {
        float o = bo[j];
        #pragma unroll 4
        for (int i = 0; i < 64; i++) o = fmaf(x1[i], wo[i * 28 + j], o);
        outp[b * 28 + j] = fsigmoid(o);
    }
}

// ---------------------------------------------------------------------------
extern "C" void kernel_launch(void* const* d_in, const int* in_sizes, int n_in,
                              void* d_out, int out_size, void* d_ws, size_t ws_size,
                              hipStream_t stream)
{
    const int* tokens  = (const int*)d_in[0];
    const float* emb   = (const float*)d_in[1];
    const float* wi1f  = (const float*)d_in[2];
    const float* wh1f  = (const float*)d_in[3];
    const float* bb1f  = (const float*)d_in[4];
    const float* wi1b  = (const float*)d_in[5];
    const float* wh1b  = (const float*)d_in[6];
    const float* bb1b  = (const float*)d_in[7];
    const float* wi2f  = (const float*)d_in[8];
    const float* wh2f  = (const float*)d_in[9];
    const float* bb2f  = (const float*)d_in[10];
    const float* wi2b  = (const float*)d_in[11];
    const float* wh2b  = (const float*)d_in[12];
    const float* bb2b  = (const float*)d_in[13];
    const float* wi3f  = (const float*)d_in[14];
    const float* wh3f  = (const float*)d_in[15];
    const float* bb3f  = (const float*)d_in[16];
    const float* wi3b  = (const float*)d_in[17];
    const float* wh3b  = (const float*)d_in[18];
    const float* bb3b  = (const float*)d_in[19];
    const float* wd1   = (const float*)d_in[20];
    const float* bd1   = (const float*)d_in[21];
    const float* wd2   = (const float*)d_in[22];
    const float* bd2   = (const float*)d_in[23];
    const float* wd3   = (const float*)d_in[24];
    const float* bd3   = (const float*)d_in[25];
    const float* wo    = (const float*)d_in[26];
    const float* bo    = (const float*)d_in[27];

    // Workspace (exactly 256 MiB):
    float* y    = (float*)d_ws;
    float* xpf  = y + (size_t)RTOT * 128;
    float* xpb  = xpf + (size_t)RTOT * 192;
    float* hcat = y; // alias: y dead after proj3 reads it

    const dim3 pb(192), pg(RTOT / 32);

    proj_kernel<64, true><<<pg, pb, 0, stream>>>(nullptr, tokens, emb,
                                                 wi1f, bb1f, wi1b, bb1b, xpf, xpb);
    gru_scan2<<<256, 192, 0, stream>>>(xpf, xpb, wh1f, wh1b, bb1f, bb1b,
                                       tokens, y, nullptr);
    proj_kernel<128, false><<<pg, pb, 0, stream>>>(y, nullptr, nullptr,
                                                   wi2f, bb2f, wi2b, bb2b, xpf, xpb);
    gru_scan2<<<256, 192, 0, stream>>>(xpf, xpb, wh2f, wh2b, bb2f, bb2b,
                                       tokens, y, nullptr);
    proj_kernel<128, false><<<pg, pb, 0, stream>>>(y, nullptr, nullptr,
                                                   wi3f, bb3f, wi3b, bb3b, xpf, xpb);
    gru_scan2<<<256, 192, 0, stream>>>(xpf, xpb, wh3f, wh3b, bb3f, bb3b,
                                       tokens, nullptr, hcat);
    mlp_kernel<<<256, 64, 0, stream>>>(hcat, wd1, bd1, wd2, bd2, wd3, bd3,
                                       wo, bo, (float*)d_out);
}